// Round 2
// baseline (203.279 us; speedup 1.0000x reference)
//
#include <hip/hip_runtime.h>
#include <hip/hip_bf16.h>

#define M_TOTAL 65536
#define HIDDEN  1024
#define N_TOTAL 152
#define OFF_CLS (M_TOTAL * 8)                  // 524288
#define OFF_REG (OFF_CLS + M_TOTAL * 128)      // 8912896

typedef __attribute__((ext_vector_type(8))) short  bf16x8;
typedef __attribute__((ext_vector_type(4))) float  f32x4;
typedef __attribute__((ext_vector_type(4))) unsigned short u16x4;

__device__ __forceinline__ short bfbits(float f) {
    __hip_bfloat16 h = __float2bfloat16(f);     // RNE; compiler packs pairs to v_cvt_pk_bf16_f32
    return *reinterpret_cast<short*>(&h);
}

// ---- pre-kernel: fuse conf_w/cls_w/reg_w -> bf16 W[160][1024] in ws (rows 152..159 zero) ----
__global__ void convert_w_kernel(const float* __restrict__ conf_w,
                                 const float* __restrict__ cls_w,
                                 const float* __restrict__ reg_w,
                                 unsigned short* __restrict__ wbf) {
    const int r = blockIdx.x;        // 0..159
    const int c = threadIdx.x * 4;   // 256 threads * 4 = 1024
    const float* src;
    if      (r <   8) src = conf_w + (size_t)r * HIDDEN;
    else if (r < 136) src = cls_w  + (size_t)(r -   8) * HIDDEN;
    else if (r < 152) src = reg_w  + (size_t)(r - 136) * HIDDEN;
    else              src = nullptr;
    unsigned short* dst = wbf + (size_t)r * HIDDEN;
    u16x4 o;
    if (src) {
        f32x4 v = *(const f32x4*)(src + c);
        o[0] = (unsigned short)bfbits(v[0]); o[1] = (unsigned short)bfbits(v[1]);
        o[2] = (unsigned short)bfbits(v[2]); o[3] = (unsigned short)bfbits(v[3]);
    } else {
        o[0] = 0; o[1] = 0; o[2] = 0; o[3] = 0;
    }
    *(u16x4*)(dst + c) = o;
}

// ---- main kernel: per-wave 16 rows x all 152 cols; no LDS, no barriers;
//      2-deep A prefetch (named stages, K unrolled by 64), 4 waves/SIMD ----
__global__ __launch_bounds__(256, 4) void ssd_mfma_kernel(
    const float* __restrict__ hs,
    const unsigned short* __restrict__ wbf,
    const float* __restrict__ conf_b,
    const float* __restrict__ cls_b,
    const float* __restrict__ reg_b,
    float* __restrict__ out) {

    const int tid  = threadIdx.x;
    const int wave = tid >> 6;
    const int lane = tid & 63;
    const int c    = lane & 15;   // A row-in-tile / B col-in-tile / D col
    const int kg   = lane >> 4;   // k-group 0..3

    const int Rbase = blockIdx.x * 64 + wave * 16;

    const float* ap          = hs  + (size_t)(Rbase + c) * HIDDEN + kg * 8;
    const unsigned short* bp = wbf + (size_t)c * HIDDEN + kg * 8;

    f32x4 acc[10];
    #pragma unroll
    for (int nt = 0; nt < 10; ++nt) {
        f32x4 z = {0.f, 0.f, 0.f, 0.f};
        acc[nt] = z;
    }

    // two named A stages: even (kk) and odd (kk+32)
    f32x4 e_lo = *(const f32x4*)(ap);
    f32x4 e_hi = *(const f32x4*)(ap + 4);
    f32x4 o_lo = *(const f32x4*)(ap + 32);
    f32x4 o_hi = *(const f32x4*)(ap + 36);

    for (int kk = 0; kk < HIDDEN; kk += 64) {
        // ---------- even half: K = kk .. kk+31 ----------
        bf16x8 bfragE[10];
        #pragma unroll
        for (int nt = 0; nt < 10; ++nt)
            bfragE[nt] = *(const bf16x8*)(bp + kk + nt * 16 * HIDDEN);

        bf16x8 afE;
        #pragma unroll
        for (int j = 0; j < 4; ++j) {
            afE[j]     = bfbits(e_lo[j]);
            afE[4 + j] = bfbits(e_hi[j]);
        }
        if (kk + 64 < HIDDEN) {                 // prefetch next even chunk
            e_lo = *(const f32x4*)(ap + kk + 64);
            e_hi = *(const f32x4*)(ap + kk + 68);
        }
        #pragma unroll
        for (int nt = 0; nt < 10; ++nt)
            acc[nt] = __builtin_amdgcn_mfma_f32_16x16x32_bf16(afE, bfragE[nt], acc[nt], 0, 0, 0);

        // ---------- odd half: K = kk+32 .. kk+63 ----------
        bf16x8 bfragO[10];
        #pragma unroll
        for (int nt = 0; nt < 10; ++nt)
            bfragO[nt] = *(const bf16x8*)(bp + kk + 32 + nt * 16 * HIDDEN);

        bf16x8 afO;
        #pragma unroll
        for (int j = 0; j < 4; ++j) {
            afO[j]     = bfbits(o_lo[j]);
            afO[4 + j] = bfbits(o_hi[j]);
        }
        if (kk + 96 < HIDDEN) {                 // prefetch next odd chunk
            o_lo = *(const f32x4*)(ap + kk + 96);
            o_hi = *(const f32x4*)(ap + kk + 100);
        }
        #pragma unroll
        for (int nt = 0; nt < 10; ++nt)
            acc[nt] = __builtin_amdgcn_mfma_f32_16x16x32_bf16(afO, bfragO[nt], acc[nt], 0, 0, 0);
    }

    // epilogue: bias + scatter into conf/cls/reg regions (D row = kg*4+i, col = c)
    #pragma unroll
    for (int nt = 0; nt < 10; ++nt) {
        const int n = nt * 16 + c;
        if (n >= N_TOTAL) continue;             // pad cols 152..159
        float bias; size_t obase; int ostride;
        if      (n <   8) { bias = conf_b[n];       obase = (size_t)n;                   ostride = 8;   }
        else if (n < 136) { bias = cls_b[n - 8];    obase = OFF_CLS + (size_t)(n - 8);   ostride = 128; }
        else              { bias = reg_b[n - 136];  obase = OFF_REG + (size_t)(n - 136); ostride = 16;  }
        const int mb = Rbase + kg * 4;
        #pragma unroll
        for (int i = 0; i < 4; ++i)
            __builtin_nontemporal_store(acc[nt][i] + bias,
                                        out + obase + (size_t)(mb + i) * ostride);
    }
}

// ---- exact fp32 fallback (only if ws too small; correctness insurance) ----
__global__ void ssd_naive_kernel(const float* __restrict__ hs,
                                 const float* __restrict__ conf_w, const float* __restrict__ conf_b,
                                 const float* __restrict__ cls_w,  const float* __restrict__ cls_b,
                                 const float* __restrict__ reg_w,  const float* __restrict__ reg_b,
                                 float* __restrict__ out) {
    const long long total = (long long)M_TOTAL * N_TOTAL;
    for (long long idx = blockIdx.x * 256LL + threadIdx.x; idx < total;
         idx += (long long)gridDim.x * 256LL) {
        const int m = (int)(idx / N_TOTAL);
        const int n = (int)(idx % N_TOTAL);
        const float* w; float b; size_t o;
        if      (n <   8) { w = conf_w + (size_t)n * HIDDEN;         b = conf_b[n];       o = (size_t)m * 8 + n; }
        else if (n < 136) { w = cls_w + (size_t)(n - 8) * HIDDEN;    b = cls_b[n - 8];    o = OFF_CLS + (size_t)m * 128 + (n - 8); }
        else              { w = reg_w + (size_t)(n - 136) * HIDDEN;  b = reg_b[n - 136];  o = OFF_REG + (size_t)m * 16 + (n - 136); }
        const float* x = hs + (size_t)m * HIDDEN;
        float s = 0.f;
        for (int k = 0; k < HIDDEN; k += 4) {
            f32x4 xv = *(const f32x4*)(x + k);
            f32x4 wv = *(const f32x4*)(w + k);
            s += xv[0] * wv[0] + xv[1] * wv[1] + xv[2] * wv[2] + xv[3] * wv[3];
        }
        out[o] = s + b;
    }
}

extern "C" void kernel_launch(void* const* d_in, const int* in_sizes, int n_in,
                              void* d_out, int out_size, void* d_ws, size_t ws_size,
                              hipStream_t stream) {
    const float* hs     = (const float*)d_in[0];
    const float* conf_w = (const float*)d_in[1];
    const float* conf_b = (const float*)d_in[2];
    const float* cls_w  = (const float*)d_in[3];
    const float* cls_b  = (const float*)d_in[4];
    const float* reg_w  = (const float*)d_in[5];
    const float* reg_b  = (const float*)d_in[6];
    float* out = (float*)d_out;

    const size_t ws_needed = 160 * (size_t)HIDDEN * sizeof(unsigned short); // 320 KB
    if (d_ws && ws_size >= ws_needed) {
        unsigned short* wbf = (unsigned short*)d_ws;
        convert_w_kernel<<<160, 256, 0, stream>>>(conf_w, cls_w, reg_w, wbf);
        ssd_mfma_kernel<<<1024, 256, 0, stream>>>(hs, wbf, conf_b, cls_b, reg_b, out);
    } else {
        ssd_naive_kernel<<<2048, 256, 0, stream>>>(hs, conf_w, conf_b,
                                                   cls_w, cls_b, reg_w, reg_b, out);
    }
}

// Round 3
// 84.093 us; speedup vs baseline: 2.4173x; 2.4173x over previous
//
#include <hip/hip_runtime.h>
#include <hip/hip_bf16.h>

#define M_TOTAL 65536
#define HIDDEN  1024
#define N_TOTAL 152
#define NPAD    160
#define OFF_CLS (M_TOTAL * 8)                  // 524288
#define OFF_REG (OFF_CLS + M_TOTAL * 128)      // 8912896

#define BK      64
#define NCHUNK  (HIDDEN / BK)                  // 16
#define CHUNK_BYTES (NPAD * BK * 2)            // 20480 per buffer

typedef __attribute__((ext_vector_type(8))) short  bf16x8;
typedef __attribute__((ext_vector_type(4))) float  f32x4;
typedef __attribute__((ext_vector_type(4))) unsigned short u16x4;

__device__ __forceinline__ short bfbits(float f) {
    __hip_bfloat16 h = __float2bfloat16(f);     // RNE; pairs fold to v_cvt_pk_bf16_f32
    return *reinterpret_cast<short*>(&h);
}

// ---- pre-kernel: fuse conf_w/cls_w/reg_w -> bf16 W[160][1024] in ws (rows 152..159 zero) ----
__global__ void convert_w_kernel(const float* __restrict__ conf_w,
                                 const float* __restrict__ cls_w,
                                 const float* __restrict__ reg_w,
                                 unsigned short* __restrict__ wbf) {
    const int r = blockIdx.x;        // 0..159
    const int c = threadIdx.x * 4;   // 256 threads * 4 = 1024
    const float* src;
    if      (r <   8) src = conf_w + (size_t)r * HIDDEN;
    else if (r < 136) src = cls_w  + (size_t)(r -   8) * HIDDEN;
    else if (r < 152) src = reg_w  + (size_t)(r - 136) * HIDDEN;
    else              src = nullptr;
    unsigned short* dst = wbf + (size_t)r * HIDDEN;
    u16x4 o;
    if (src) {
        f32x4 v = *(const f32x4*)(src + c);
        o[0] = (unsigned short)bfbits(v[0]); o[1] = (unsigned short)bfbits(v[1]);
        o[2] = (unsigned short)bfbits(v[2]); o[3] = (unsigned short)bfbits(v[3]);
    } else {
        o[0] = 0; o[1] = 0; o[2] = 0; o[3] = 0;
    }
    *(u16x4*)(dst + c) = o;
}

// ---- main kernel: block = 64 rows (4 waves x 16 rows), all 152 cols.
//      B double-buffered in LDS via global_load_lds (XOR-swizzled source, rule #21);
//      A register-prefetched one K-chunk ahead. No forced launch_bounds min-waves. ----
__global__ __launch_bounds__(256) void ssd_mfma_kernel(
    const float* __restrict__ hs,
    const unsigned short* __restrict__ wbf,
    const float* __restrict__ conf_b,
    const float* __restrict__ cls_b,
    const float* __restrict__ reg_b,
    float* __restrict__ out) {

    __shared__ __align__(16) unsigned char smem[2 * CHUNK_BYTES];   // 40 KB

    const int tid  = threadIdx.x;
    const int wave = tid >> 6;
    const int lane = tid & 63;
    const int c    = lane & 15;   // A row-in-tile / B col-in-tile / D col
    const int kg   = lane >> 4;   // k-group 0..3

    const int Rbase = blockIdx.x * 64 + wave * 16;

    const float* ap = hs + (size_t)(Rbase + c) * HIDDEN + kg * 8;

    // --- staging lane constants (write side of the swizzle) ---
    // LDS slot for lane l (per call): row = i*32 + wave*8 + (l>>3), stored chunk s = l&7.
    // Stored chunk s must contain logical chunk s ^ (row&7); row&7 == l>>3.
    const int srow   = lane >> 3;                 // 0..7
    const int schunk = (lane & 7) ^ srow;         // logical 16B-chunk to fetch
    const unsigned short* gstage =
        wbf + (size_t)(wave * 8 + srow) * HIDDEN + schunk * 8;
    const int ldsw = wave * 1024;                 // wave-uniform LDS base (bytes), + i*4096

    // --- read bases (read side of the swizzle), bytes within a buffer ---
    // row = nt*16 + c, logical chunk = ks*4 + kg  ->  stored chunk = (ks*4+kg) ^ (c&7)
    const int rdb0 = c * 128 + ((kg       ^ (c & 7)) * 16);
    const int rdb1 = c * 128 + (((4 | kg) ^ (c & 7)) * 16);

    f32x4 acc[10];
    #pragma unroll
    for (int nt = 0; nt < 10; ++nt) {
        f32x4 z = {0.f, 0.f, 0.f, 0.f};
        acc[nt] = z;
    }

    // A stages for chunk 0 (even = first k-step, odd = second)
    f32x4 e_lo = *(const f32x4*)(ap);
    f32x4 e_hi = *(const f32x4*)(ap + 4);
    f32x4 o_lo = *(const f32x4*)(ap + 32);
    f32x4 o_hi = *(const f32x4*)(ap + 36);

    // stage B chunk 0 into buffer 0 (5 calls x 1 KB per wave = rows wave*8+{0..7} each i)
    #pragma unroll
    for (int i = 0; i < 5; ++i)
        __builtin_amdgcn_global_load_lds(
            (const __attribute__((address_space(1))) void*)(gstage + (size_t)i * 32 * HIDDEN),
            (__attribute__((address_space(3))) void*)(smem + ldsw + i * 4096),
            16, 0, 0);
    __syncthreads();   // drains vmcnt then barriers

    int cur = 0;
    for (int t = 0; t < NCHUNK; ++t) {
        const int kb = t * BK;
        const int kn = (t + 1 < NCHUNK) ? kb + BK : kb;

        // A prefetch for next chunk (HBM; a full compute phase + barrier away)
        f32x4 ne_lo = *(const f32x4*)(ap + kn);
        f32x4 ne_hi = *(const f32x4*)(ap + kn + 4);
        f32x4 no_lo = *(const f32x4*)(ap + kn + 32);
        f32x4 no_hi = *(const f32x4*)(ap + kn + 36);

        // B stage for next chunk into the other buffer (L2-resident source)
        if (t + 1 < NCHUNK) {
            const int nb = (cur ^ 1) * CHUNK_BYTES;
            #pragma unroll
            for (int i = 0; i < 5; ++i)
                __builtin_amdgcn_global_load_lds(
                    (const __attribute__((address_space(1))) void*)(gstage + (size_t)i * 32 * HIDDEN + kb + BK),
                    (__attribute__((address_space(3))) void*)(smem + nb + ldsw + i * 4096),
                    16, 0, 0);
        }

        const unsigned char* sb = smem + cur * CHUNK_BYTES;

        // ---------- k-step 0 ----------
        bf16x8 bfrag[10];
        #pragma unroll
        for (int nt = 0; nt < 10; ++nt)
            bfrag[nt] = *(const bf16x8*)(sb + rdb0 + nt * 2048);
        bf16x8 af;
        #pragma unroll
        for (int j = 0; j < 4; ++j) {
            af[j]     = bfbits(e_lo[j]);
            af[4 + j] = bfbits(e_hi[j]);
        }
        #pragma unroll
        for (int nt = 0; nt < 10; ++nt)
            acc[nt] = __builtin_amdgcn_mfma_f32_16x16x32_bf16(af, bfrag[nt], acc[nt], 0, 0, 0);

        // ---------- k-step 1 ----------
        #pragma unroll
        for (int nt = 0; nt < 10; ++nt)
            bfrag[nt] = *(const bf16x8*)(sb + rdb1 + nt * 2048);
        #pragma unroll
        for (int j = 0; j < 4; ++j) {
            af[j]     = bfbits(o_lo[j]);
            af[4 + j] = bfbits(o_hi[j]);
        }
        #pragma unroll
        for (int nt = 0; nt < 10; ++nt)
            acc[nt] = __builtin_amdgcn_mfma_f32_16x16x32_bf16(af, bfrag[nt], acc[nt], 0, 0, 0);

        __syncthreads();   // next buffer staged; everyone done reading cur
        cur ^= 1;
        e_lo = ne_lo; e_hi = ne_hi; o_lo = no_lo; o_hi = no_hi;
    }

    // epilogue: bias + scatter into conf/cls/reg regions (D row = kg*4+i, col = nt*16+c)
    #pragma unroll
    for (int nt = 0; nt < 10; ++nt) {
        const int n = nt * 16 + c;
        if (n >= N_TOTAL) continue;             // pad cols 152..159
        float bias; size_t obase; int ostride;
        if      (n <   8) { bias = conf_b[n];       obase = (size_t)n;                   ostride = 8;   }
        else if (n < 136) { bias = cls_b[n - 8];    obase = OFF_CLS + (size_t)(n - 8);   ostride = 128; }
        else              { bias = reg_b[n - 136];  obase = OFF_REG + (size_t)(n - 136); ostride = 16;  }
        const int mb = Rbase + kg * 4;
        #pragma unroll
        for (int i = 0; i < 4; ++i)
            __builtin_nontemporal_store(acc[nt][i] + bias,
                                        out + obase + (size_t)(mb + i) * ostride);
    }
}

// ---- exact fp32 fallback (only if ws too small; correctness insurance) ----
__global__ void ssd_naive_kernel(const float* __restrict__ hs,
                                 const float* __restrict__ conf_w, const float* __restrict__ conf_b,
                                 const float* __restrict__ cls_w,  const float* __restrict__ cls_b,
                                 const float* __restrict__ reg_w,  const float* __restrict__ reg_b,
                                 float* __restrict__ out) {
    const long long total = (long long)M_TOTAL * N_TOTAL;
    for (long long idx = blockIdx.x * 256LL + threadIdx.x; idx < total;
         idx += (long long)gridDim.x * 256LL) {
        const int m = (int)(idx / N_TOTAL);
        const int n = (int)(idx % N_TOTAL);
        const float* w; float b; size_t o;
        if      (n <   8) { w = conf_w + (size_t)n * HIDDEN;         b = conf_b[n];       o = (size_t)m * 8 + n; }
        else if (n < 136) { w = cls_w + (size_t)(n - 8) * HIDDEN;    b = cls_b[n - 8];    o = OFF_CLS + (size_t)m * 128 + (n - 8); }
        else              { w = reg_w + (size_t)(n - 136) * HIDDEN;  b = reg_b[n - 136];  o = OFF_REG + (size_t)m * 16 + (n - 136); }
        const float* x = hs + (size_t)m * HIDDEN;
        float s = 0.f;
        for (int k = 0; k < HIDDEN; k += 4) {
            f32x4 xv = *(const f32x4*)(x + k);
            f32x4 wv = *(const f32x4*)(w + k);
            s += xv[0] * wv[0] + xv[1] * wv[1] + xv[2] * wv[2] + xv[3] * wv[3];
        }
        out[o] = s + b;
    }
}

extern "C" void kernel_launch(void* const* d_in, const int* in_sizes, int n_in,
                              void* d_out, int out_size, void* d_ws, size_t ws_size,
                              hipStream_t stream) {
    const float* hs     = (const float*)d_in[0];
    const float* conf_w = (const float*)d_in[1];
    const float* conf_b = (const float*)d_in[2];
    const float* cls_w  = (const float*)d_in[3];
    const float* cls_b  = (const float*)d_in[4];
    const float* reg_w  = (const float*)d_in[5];
    const float* reg_b  = (const float*)d_in[6];
    float* out = (float*)d_out;

    const size_t ws_needed = (size_t)NPAD * HIDDEN * sizeof(unsigned short); // 320 KB
    if (d_ws && ws_size >= ws_needed) {
        unsigned short* wbf = (unsigned short*)d_ws;
        convert_w_kernel<<<160, 256, 0, stream>>>(conf_w, cls_w, reg_w, wbf);
        ssd_mfma_kernel<<<M_TOTAL / 64, 256, 0, stream>>>(hs, wbf, conf_b, cls_b, reg_b, out);
    } else {
        ssd_naive_kernel<<<2048, 256, 0, stream>>>(hs, conf_w, conf_b,
                                                   cls_w, cls_b, reg_w, reg_b, out);
    }
}

// Round 4
// 73.604 us; speedup vs baseline: 2.7618x; 1.1425x over previous
//
#include <hip/hip_runtime.h>
#include <hip/hip_bf16.h>

#define M_TOTAL 65536
#define HIDDEN  1024
#define N_TOTAL 152
#define NPAD    160
#define OFF_CLS (M_TOTAL * 8)                  // 524288
#define OFF_REG (OFF_CLS + M_TOTAL * 128)      // 8912896

#define BK      64
#define CHUNK_BYTES (NPAD * BK * 2)            // 20480 per buffer

typedef __attribute__((ext_vector_type(8))) short  bf16x8;
typedef __attribute__((ext_vector_type(4))) float  f32x4;
typedef __attribute__((ext_vector_type(4))) unsigned short u16x4;

__device__ __forceinline__ short bfbits(float f) {
    __hip_bfloat16 h = __float2bfloat16(f);     // RNE; pairs fold to v_cvt_pk_bf16_f32
    return *reinterpret_cast<short*>(&h);
}

// ---- pre-kernel: fuse conf_w/cls_w/reg_w -> bf16 W[160][1024] in ws (rows 152..159 zero) ----
__global__ void convert_w_kernel(const float* __restrict__ conf_w,
                                 const float* __restrict__ cls_w,
                                 const float* __restrict__ reg_w,
                                 unsigned short* __restrict__ wbf) {
    const int r = blockIdx.x;        // 0..159
    const int c = threadIdx.x * 4;   // 256 threads * 4 = 1024
    const float* src;
    if      (r <   8) src = conf_w + (size_t)r * HIDDEN;
    else if (r < 136) src = cls_w  + (size_t)(r -   8) * HIDDEN;
    else if (r < 152) src = reg_w  + (size_t)(r - 136) * HIDDEN;
    else              src = nullptr;
    unsigned short* dst = wbf + (size_t)r * HIDDEN;
    u16x4 o;
    if (src) {
        f32x4 v = *(const f32x4*)(src + c);
        o[0] = (unsigned short)bfbits(v[0]); o[1] = (unsigned short)bfbits(v[1]);
        o[2] = (unsigned short)bfbits(v[2]); o[3] = (unsigned short)bfbits(v[3]);
    } else {
        o[0] = 0; o[1] = 0; o[2] = 0; o[3] = 0;
    }
    *(u16x4*)(dst + c) = o;
}

// stage next B chunk: 5 x global_load_lds (wave-linear dest, XOR-pre-swizzled source)
#define STAGE_B(KOFF, BUFOFF)                                                              \
    _Pragma("unroll")                                                                      \
    for (int i = 0; i < 5; ++i)                                                            \
        __builtin_amdgcn_global_load_lds(                                                  \
            (const __attribute__((address_space(1))) void*)(gstage + (size_t)i * 32 * HIDDEN + (KOFF)), \
            (__attribute__((address_space(3))) void*)(smem + (BUFOFF) + ldsw + i * 4096),  \
            16, 0, 0);

#define CVT(AF, LO, HI)                                                                    \
    do { _Pragma("unroll")                                                                 \
         for (int j = 0; j < 4; ++j) { AF[j] = bfbits((LO)[j]); AF[4+j] = bfbits((HI)[j]); } \
    } while (0)

// one BK=64 chunk: 2 k-steps x 10 N-tiles, reading swizzled LDS buffer at SB
#define COMPUTE_CHUNK(SB)                                                                  \
    do {                                                                                   \
        bf16x8 bfrag[10];                                                                  \
        _Pragma("unroll")                                                                  \
        for (int nt = 0; nt < 10; ++nt)                                                    \
            bfrag[nt] = *(const bf16x8*)((SB) + rdb0 + nt * 2048);                         \
        _Pragma("unroll")                                                                  \
        for (int nt = 0; nt < 10; ++nt)                                                    \
            acc[nt] = __builtin_amdgcn_mfma_f32_16x16x32_bf16(afE, bfrag[nt], acc[nt], 0, 0, 0); \
        _Pragma("unroll")                                                                  \
        for (int nt = 0; nt < 10; ++nt)                                                    \
            bfrag[nt] = *(const bf16x8*)((SB) + rdb1 + nt * 2048);                         \
        _Pragma("unroll")                                                                  \
        for (int nt = 0; nt < 10; ++nt)                                                    \
            acc[nt] = __builtin_amdgcn_mfma_f32_16x16x32_bf16(afO, bfrag[nt], acc[nt], 0, 0, 0); \
    } while (0)

// ---- main kernel: block = 64 rows (4 waves x 16 rows), all 152 cols.
//      B double-buffered in LDS; counted vmcnt(4) barriers keep the A stream
//      in flight across phases (T4); last pair peeled (single vmcnt(0)). ----
__global__ __launch_bounds__(256) void ssd_mfma_kernel(
    const float* __restrict__ hs,
    const unsigned short* __restrict__ wbf,
    const float* __restrict__ conf_b,
    const float* __restrict__ cls_b,
    const float* __restrict__ reg_b,
    float* __restrict__ out) {

    __shared__ __align__(16) unsigned char smem[2 * CHUNK_BYTES];   // 40 KB

    const int tid  = threadIdx.x;
    const int wave = tid >> 6;
    const int lane = tid & 63;
    const int c    = lane & 15;   // A row-in-tile / B col-in-tile / D col
    const int kg   = lane >> 4;   // k-group 0..3

    const int Rbase = blockIdx.x * 64 + wave * 16;
    const float* ap = hs + (size_t)(Rbase + c) * HIDDEN + kg * 8;

    // staging lane constants (write side of the swizzle; rule #21)
    const int srow   = lane >> 3;                 // 0..7
    const int schunk = (lane & 7) ^ srow;         // logical 16B-chunk to fetch
    const unsigned short* gstage =
        wbf + (size_t)(wave * 8 + srow) * HIDDEN + schunk * 8;
    const int ldsw = wave * 1024;                 // wave-uniform LDS base (bytes)

    // read bases (swizzled), bytes within a buffer
    const int rdb0 = c * 128 + ((kg       ^ (c & 7)) * 16);
    const int rdb1 = c * 128 + (((4 | kg) ^ (c & 7)) * 16);

    f32x4 acc[10];
    #pragma unroll
    for (int nt = 0; nt < 10; ++nt) {
        f32x4 z = {0.f, 0.f, 0.f, 0.f};
        acc[nt] = z;
    }

    // -------- prologue: B chunk0 -> buf0; A chunks 0,1 -> named sets --------
    STAGE_B(0, 0);
    f32x4 s0a = *(const f32x4*)(ap);        f32x4 s0b = *(const f32x4*)(ap + 4);
    f32x4 s0c = *(const f32x4*)(ap + 32);   f32x4 s0d = *(const f32x4*)(ap + 36);
    f32x4 s1a = *(const f32x4*)(ap + 64);   f32x4 s1b = *(const f32x4*)(ap + 68);
    f32x4 s1c = *(const f32x4*)(ap + 96);   f32x4 s1d = *(const f32x4*)(ap + 100);
    __builtin_amdgcn_sched_barrier(0);
    asm volatile("s_waitcnt vmcnt(8)");     // B chunk0 done; 8 A loads still in flight
    __builtin_amdgcn_s_barrier();

    bf16x8 afE, afO;

    // -------- main loop: 7 pairs of chunks, fully pipelined --------
    for (int t = 0; t < 7; ++t) {
        const int kb = t * 128;

        // half 0: compute chunk kb from buf0; stage B(kb+64)->buf1; A(kb+128)->set0
        STAGE_B(kb + 64, CHUNK_BYTES);
        __builtin_amdgcn_sched_barrier(0);
        CVT(afE, s0a, s0b); CVT(afO, s0c, s0d);
        s0a = *(const f32x4*)(ap + kb + 128);  s0b = *(const f32x4*)(ap + kb + 132);
        s0c = *(const f32x4*)(ap + kb + 160);  s0d = *(const f32x4*)(ap + kb + 164);
        __builtin_amdgcn_sched_barrier(0);
        COMPUTE_CHUNK(smem);
        __builtin_amdgcn_sched_barrier(0);
        asm volatile("s_waitcnt vmcnt(4)");    // B(kb+64) done; set0 loads stay in flight
        __builtin_amdgcn_s_barrier();

        // half 1: compute chunk kb+64 from buf1; stage B(kb+128)->buf0; A(kb+192)->set1
        STAGE_B(kb + 128, 0);
        __builtin_amdgcn_sched_barrier(0);
        CVT(afE, s1a, s1b); CVT(afO, s1c, s1d);
        s1a = *(const f32x4*)(ap + kb + 192);  s1b = *(const f32x4*)(ap + kb + 196);
        s1c = *(const f32x4*)(ap + kb + 224);  s1d = *(const f32x4*)(ap + kb + 228);
        __builtin_amdgcn_sched_barrier(0);
        COMPUTE_CHUNK(smem + CHUNK_BYTES);
        __builtin_amdgcn_sched_barrier(0);
        asm volatile("s_waitcnt vmcnt(4)");    // B(kb+128) done; set1 loads stay in flight
        __builtin_amdgcn_s_barrier();
    }

    // -------- peeled pair 7: chunks 896 (buf0) and 960 (buf1) --------
    STAGE_B(960, CHUNK_BYTES);
    __builtin_amdgcn_sched_barrier(0);
    CVT(afE, s0a, s0b); CVT(afO, s0c, s0d);    // chunk 896
    __builtin_amdgcn_sched_barrier(0);
    COMPUTE_CHUNK(smem);
    __builtin_amdgcn_sched_barrier(0);
    asm volatile("s_waitcnt vmcnt(0)");        // the only full drain, once
    __builtin_amdgcn_s_barrier();
    CVT(afE, s1a, s1b); CVT(afO, s1c, s1d);    // chunk 960
    COMPUTE_CHUNK(smem + CHUNK_BYTES);

    // -------- epilogue: bias + scatter (D row = kg*4+i, col = nt*16+c) --------
    #pragma unroll
    for (int nt = 0; nt < 10; ++nt) {
        const int n = nt * 16 + c;
        if (n >= N_TOTAL) continue;             // pad cols 152..159
        float bias; size_t obase; int ostride;
        if      (n <   8) { bias = conf_b[n];       obase = (size_t)n;                   ostride = 8;   }
        else if (n < 136) { bias = cls_b[n - 8];    obase = OFF_CLS + (size_t)(n - 8);   ostride = 128; }
        else              { bias = reg_b[n - 136];  obase = OFF_REG + (size_t)(n - 136); ostride = 16;  }
        const int mb = Rbase + kg * 4;
        #pragma unroll
        for (int i = 0; i < 4; ++i)
            __builtin_nontemporal_store(acc[nt][i] + bias,
                                        out + obase + (size_t)(mb + i) * ostride);
    }
}

// ---- exact fp32 fallback (only if ws too small; correctness insurance) ----
__global__ void ssd_naive_kernel(const float* __restrict__ hs,
                                 const float* __restrict__ conf_w, const float* __restrict__ conf_b,
                                 const float* __restrict__ cls_w,  const float* __restrict__ cls_b,
                                 const float* __restrict__ reg_w,  const float* __restrict__ reg_b,
                                 float* __restrict__ out) {
    const long long total = (long long)M_TOTAL * N_TOTAL;
    for (long long idx = blockIdx.x * 256LL + threadIdx.x; idx < total;
         idx += (long long)gridDim.x * 256LL) {
        const int m = (int)(idx / N_TOTAL);
        const int n = (int)(idx % N_TOTAL);
        const float* w; float b; size_t o;
        if      (n <   8) { w = conf_w + (size_t)n * HIDDEN;         b = conf_b[n];       o = (size_t)m * 8 + n; }
        else if (n < 136) { w = cls_w + (size_t)(n - 8) * HIDDEN;    b = cls_b[n - 8];    o = OFF_CLS + (size_t)m * 128 + (n - 8); }
        else              { w = reg_w + (size_t)(n - 136) * HIDDEN;  b = reg_b[n - 136];  o = OFF_REG + (size_t)m * 16 + (n - 136); }
        const float* x = hs + (size_t)m * HIDDEN;
        float s = 0.f;
        for (int k = 0; k < HIDDEN; k += 4) {
            f32x4 xv = *(const f32x4*)(x + k);
            f32x4 wv = *(const f32x4*)(w + k);
            s += xv[0] * wv[0] + xv[1] * wv[1] + xv[2] * wv[2] + xv[3] * wv[3];
        }
        out[o] = s + b;
    }
}

extern "C" void kernel_launch(void* const* d_in, const int* in_sizes, int n_in,
                              void* d_out, int out_size, void* d_ws, size_t ws_size,
                              hipStream_t stream) {
    const float* hs     = (const float*)d_in[0];
    const float* conf_w = (const float*)d_in[1];
    const float* conf_b = (const float*)d_in[2];
    const float* cls_w  = (const float*)d_in[3];
    const float* cls_b  = (const float*)d_in[4];
    const float* reg_w  = (const float*)d_in[5];
    const float* reg_b  = (const float*)d_in[6];
    float* out = (float*)d_out;

    const size_t ws_needed = (size_t)NPAD * HIDDEN * sizeof(unsigned short); // 320 KB
    if (d_ws && ws_size >= ws_needed) {
        unsigned short* wbf = (unsigned short*)d_ws;
        convert_w_kernel<<<160, 256, 0, stream>>>(conf_w, cls_w, reg_w, wbf);
        ssd_mfma_kernel<<<M_TOTAL / 64, 256, 0, stream>>>(hs, wbf, conf_b, cls_b, reg_b, out);
    } else {
        ssd_naive_kernel<<<2048, 256, 0, stream>>>(hs, conf_w, conf_b,
                                                   cls_w, cls_b, reg_w, reg_b, out);
    }
}